// Round 3
// baseline (1477.716 us; speedup 1.0000x reference)
//
#include <hip/hip_runtime.h>
#include <hip/hip_fp16.h>

// NonLinearAttention on MI355X (gfx950), round 3.
// Shapes: N=32 mol, A=96 atoms, B=48 neighbors, F=256, D=256, H=8 heads, d=32.
// Strategy: fp16 MFMA (fp32 accum); each 2-layer MLP fused into ONE kernel
// (hidden 128x128 tiles live in LDS, never HBM); m97-style staging
// (global_load_lds width=16, linear LDS, 2-barrier phases); fused attention.
// Workspace (~305 MB):
//   Xv  [147456][512] fp16 = fp16(b) || fp16(rbf)   151.0 MB
//   kb  [147456][256] fp16                            75.5 MB
//   vb  [147456][256] fp16                            75.5 MB
//   ah/qh [3072][256] fp16 + 6 transposed weight mats  ~3.3 MB

using half_t = _Float16;
using half8  = __attribute__((ext_vector_type(8))) _Float16;
using f32x4  = __attribute__((ext_vector_type(4))) float;

#define R_ROWS 147456   // N*A*B
#define Q_ROWS 3072     // N*A

// async global->LDS, 16B/lane; LDS dest wave-uniform (HW adds lane*16).
__device__ __forceinline__ void gld_lds16(const void* g, void* l) {
  __builtin_amdgcn_global_load_lds((const __attribute__((address_space(1))) void*)g,
                                   (__attribute__((address_space(3))) void*)l,
                                   16, 0, 0);
}

// ---------------------------------------------------------------- prep kernels

// Xv[r][0:256]=fp16(b[r]), Xv[r][256:512]=fp16(rbf[r]). 8 elems/thread.
__global__ __launch_bounds__(256)
void build_xv(const float* __restrict__ b, const float* __restrict__ rbf,
              half_t* __restrict__ xv)
{
  int i  = blockIdx.x * 256 + threadIdx.x;
  int r  = i >> 5;
  int c8 = (i & 31) << 3;
  const float4* pb = (const float4*)(b   + (size_t)r * 256 + c8);
  const float4* pr = (const float4*)(rbf + (size_t)r * 256 + c8);
  float4 b0 = pb[0], b1 = pb[1];
  float4 r0 = pr[0], r1 = pr[1];
  union { half_t h[8]; uint4 u; } k0, k1;
  k0.h[0]=(half_t)b0.x; k0.h[1]=(half_t)b0.y; k0.h[2]=(half_t)b0.z; k0.h[3]=(half_t)b0.w;
  k0.h[4]=(half_t)b1.x; k0.h[5]=(half_t)b1.y; k0.h[6]=(half_t)b1.z; k0.h[7]=(half_t)b1.w;
  k1.h[0]=(half_t)r0.x; k1.h[1]=(half_t)r0.y; k1.h[2]=(half_t)r0.z; k1.h[3]=(half_t)r0.w;
  k1.h[4]=(half_t)r1.x; k1.h[5]=(half_t)r1.y; k1.h[6]=(half_t)r1.z; k1.h[7]=(half_t)r1.w;
  *(uint4*)(xv + (size_t)r * 512 + c8)       = k0.u;
  *(uint4*)(xv + (size_t)r * 512 + 256 + c8) = k1.u;
}

__global__ __launch_bounds__(256)
void cvt_f32_f16(const float* __restrict__ in, half_t* __restrict__ o, int n8)
{
  int i = blockIdx.x * 256 + threadIdx.x;
  if (i >= n8) return;
  const float4* p = (const float4*)(in + (size_t)i * 8);
  float4 a0 = p[0], a1 = p[1];
  union { half_t h[8]; uint4 u; } k;
  k.h[0]=(half_t)a0.x; k.h[1]=(half_t)a0.y; k.h[2]=(half_t)a0.z; k.h[3]=(half_t)a0.w;
  k.h[4]=(half_t)a1.x; k.h[5]=(half_t)a1.y; k.h[6]=(half_t)a1.z; k.h[7]=(half_t)a1.w;
  *(uint4*)(o + (size_t)i * 8) = k.u;
}

// W[K][N] fp32 -> WT[N][K] fp16.
__global__ __launch_bounds__(256)
void prep_wt(const float* __restrict__ w, half_t* __restrict__ wt, int K, int N)
{
  int i = blockIdx.x * 256 + threadIdx.x;
  if (i >= K * N) return;
  int n = i / K, k = i % K;
  wt[i] = (half_t)w[(size_t)k * N + n];
}

// ------------------------------------------------------- fused 2-layer MLP
// O[M][256] = relu(X[M][:K1] @ W1 + b1) @ W2 + b2, weights pre-transposed:
// W1T [512][K1] fp16, W2T [256][512] fp16. One block = 128 rows, 4 waves.
// Per n1-tile t (4 tiles of 128 hidden cols):
//   L1: K1-loop, stage lx/lw via global_load_lds, 16 MFMA/wave/K-step -> acc1
//   write relu(acc1+b1) into lh[128][128] (XOR-swizzled, VALU both sides)
//   L2: 2 substeps of k=64: stage W2T slice (256x64), acc2 += lh @ W2T
// acc2 persists across tiles (128 VGPR) + acc1 (64) -> ~230 VGPR, cap 256.
// LDS: lx 16KB + lw 32KB + lh 32KB = 80KB -> 2 blocks/CU.
template<int KT1>
__global__ __launch_bounds__(256, 2)
void fused_mlp(const half_t* __restrict__ X, int ldx,
               const half_t* __restrict__ W1T,
               const float* __restrict__ b1,
               const half_t* __restrict__ W2T,
               const float* __restrict__ b2,
               half_t* __restrict__ O)
{
  __shared__ __align__(16) half_t lx[128 * 64];
  __shared__ __align__(16) half_t lw[256 * 64];   // L1 uses rows 0-127, L2 all 256
  __shared__ __align__(16) half_t lh[128 * 128];  // swizzled hidden tile
  const int tid  = threadIdx.x;
  const int lane = tid & 63;
  const int wid  = tid >> 6;
  const int l15  = lane & 15;
  const int lg   = lane >> 4;
  const int srow = lane >> 3;          // staging: row within 8-row chunk
  const int sbyt = (lane & 7) * 16;    // staging: byte within 128B row
  const int mt   = blockIdx.x * 128;
  const int wr1  = (wid >> 1) * 64, wc1 = (wid & 1) * 64;    // L1: 64x64/wave
  const int wr2  = (wid >> 1) * 64, wc2 = (wid & 1) * 128;   // L2: 64x128/wave

  f32x4 acc2[4][8];
#pragma unroll
  for (int i = 0; i < 4; ++i)
#pragma unroll
    for (int j = 0; j < 8; ++j)
      acc2[i][j] = (f32x4){0.f, 0.f, 0.f, 0.f};

  for (int t = 0; t < 4; ++t) {
    // ---- layer 1: acc1 = X[128, :K1] @ W1T[t*128..+128, :K1]^T
    f32x4 acc1[4][4];
#pragma unroll
    for (int i = 0; i < 4; ++i)
#pragma unroll
      for (int j = 0; j < 4; ++j)
        acc1[i][j] = (f32x4){0.f, 0.f, 0.f, 0.f};

    for (int kt = 0; kt < KT1; ++kt) {
      const int k0 = kt * 64;
#pragma unroll
      for (int it = 0; it < 4; ++it) {
        const int rbase = wid * 32 + it * 8;            // wave-uniform
        const int grow  = rbase + srow;                 // per-lane
        gld_lds16((const char*)(X + (size_t)(mt + grow) * ldx + k0) + sbyt,
                  (char*)lx + rbase * 128);
        gld_lds16((const char*)(W1T + (size_t)(t * 128 + grow) * (KT1 * 64) + k0) + sbyt,
                  (char*)lw + rbase * 128);
      }
      __syncthreads();
#pragma unroll
      for (int s = 0; s < 2; ++s) {
        const int kk2 = s * 32 + lg * 8;
        half8 af[4], bf[4];
#pragma unroll
        for (int i = 0; i < 4; ++i)
          af[i] = *(const half8*)(lx + (wr1 + i * 16 + l15) * 64 + kk2);
#pragma unroll
        for (int j = 0; j < 4; ++j)
          bf[j] = *(const half8*)(lw + (wc1 + j * 16 + l15) * 64 + kk2);
#pragma unroll
        for (int i = 0; i < 4; ++i)
#pragma unroll
          for (int j = 0; j < 4; ++j)
            acc1[i][j] = __builtin_amdgcn_mfma_f32_16x16x32_f16(af[i], bf[j], acc1[i][j], 0, 0, 0);
      }
      __syncthreads();
    }

    // ---- relu(acc1+b1) -> lh (C/D layout: col=l15, row=lg*4+r; XOR-swizzled)
#pragma unroll
    for (int j = 0; j < 4; ++j) {
      const int col = wc1 + j * 16 + l15;
      const float bv = b1[t * 128 + col];
#pragma unroll
      for (int i = 0; i < 4; ++i) {
#pragma unroll
        for (int r = 0; r < 4; ++r) {
          const int row = wr1 + i * 16 + lg * 4 + r;
          float v = fmaxf(acc1[i][j][r] + bv, 0.f);
          *(half_t*)((char*)lh + row * 256 + ((col * 2) ^ ((row & 7) << 4))) = (half_t)v;
        }
      }
    }
    __syncthreads();

    // ---- layer 2 partial: acc2 += lh[128][128] @ W2T[:, t*128..+128]^T
#pragma unroll
    for (int ss = 0; ss < 2; ++ss) {
#pragma unroll
      for (int it = 0; it < 8; ++it) {                  // stage W2T 256 rows x 64 k
        const int rbase = wid * 64 + it * 8;
        const int grow  = rbase + srow;
        gld_lds16((const char*)(W2T + (size_t)grow * 512 + t * 128 + ss * 64) + sbyt,
                  (char*)lw + rbase * 128);
      }
      __syncthreads();
#pragma unroll
      for (int s = 0; s < 2; ++s) {
        const int kb = ss * 128 + s * 64 + lg * 16;     // byte offset in lh row
        half8 af2[4];
#pragma unroll
        for (int i = 0; i < 4; ++i) {
          const int row = wr2 + i * 16 + l15;
          af2[i] = *(const half8*)((const char*)lh + row * 256 + (kb ^ ((row & 7) << 4)));
        }
#pragma unroll
        for (int j = 0; j < 8; ++j) {
          half8 bf = *(const half8*)(lw + (wc2 + j * 16 + l15) * 64 + s * 32 + lg * 8);
#pragma unroll
          for (int i = 0; i < 4; ++i)
            acc2[i][j] = __builtin_amdgcn_mfma_f32_16x16x32_f16(af2[i], bf, acc2[i][j], 0, 0, 0);
        }
      }
      __syncthreads();
    }
  }

  // ---- epilogue: O = acc2 + b2 (no relu)
#pragma unroll
  for (int j = 0; j < 8; ++j) {
    const int gc = wc2 + j * 16 + l15;
    const float bv = b2[gc];
#pragma unroll
    for (int i = 0; i < 4; ++i) {
      const int gr0 = mt + wr2 + i * 16 + lg * 4;
#pragma unroll
      for (int r = 0; r < 4; ++r)
        O[(size_t)(gr0 + r) * 256 + gc] = (half_t)(acc2[i][j][r] + bv);
    }
  }
}

// ---------------------------------------------------------------- attention
// One block (128 thr) per (n,a). Stage k,v (48x256 fp16) in padded LDS,
// logits+mask, per-head softmax over 48 neighbors, PV, residual. fp32 math.
__global__ __launch_bounds__(128)
void attn_kernel(const half_t* __restrict__ q,
                 const half_t* __restrict__ kk,
                 const half_t* __restrict__ vv,
                 const int* __restrict__ mask,
                 const float* __restrict__ a,
                 float* __restrict__ out)
{
  __shared__ __align__(16) half_t lk[48 * 264];
  __shared__ __align__(16) half_t lv[48 * 264];
  __shared__ float lq[8 * 36];
  __shared__ float lg[48 * 8];
  const int na = blockIdx.x;
  const int t  = threadIdx.x;
  const size_t base = (size_t)na * (48 * 256);

#pragma unroll
  for (int it = 0; it < 12; ++it) {
    int c = it * 128 + t;
    int row = c >> 5, c16 = (c & 31) * 16;
    uint4 dk = ((const uint4*)(kk + base))[c];
    uint4 dv = ((const uint4*)(vv + base))[c];
    *(uint4*)((char*)lk + row * 528 + c16) = dk;
    *(uint4*)((char*)lv + row * 528 + c16) = dv;
  }
  {
    float q0 = (float)q[(size_t)na * 256 + t];
    float q1 = (float)q[(size_t)na * 256 + 128 + t];
    int h0 = t >> 5, d0 = t & 31;
    lq[h0 * 36 + d0]       = q0;
    lq[(h0 + 4) * 36 + d0] = q1;
  }
  __syncthreads();

#pragma unroll
  for (int p = 0; p < 3; ++p) {
    int pr = p * 128 + t;
    int bn = pr >> 3, h = pr & 7;
    const half_t* kr = (const half_t*)((const char*)lk + bn * 528) + h * 32;
    const float*  qr = lq + h * 36;
    float s = 0.f;
#pragma unroll
    for (int d = 0; d < 32; ++d) s += qr[d] * (float)kr[d];
    if (mask[na * 48 + bn] == 0) s -= 100000.0f;
    lg[bn * 8 + h] = s;
  }
  __syncthreads();
  if (t < 8) {
    float mx = -3.0e38f;
    for (int bn = 0; bn < 48; ++bn) mx = fmaxf(mx, lg[bn * 8 + t]);
    float sm = 0.f;
    for (int bn = 0; bn < 48; ++bn) {
      float e = __expf(lg[bn * 8 + t] - mx);
      lg[bn * 8 + t] = e; sm += e;
    }
    float inv = 1.f / sm;
    for (int bn = 0; bn < 48; ++bn) lg[bn * 8 + t] *= inv;
  }
  __syncthreads();
#pragma unroll
  for (int cc = 0; cc < 2; ++cc) {
    int c = cc * 128 + t;
    int h = c >> 5;
    float s = 0.f;
#pragma unroll
    for (int bn = 0; bn < 48; ++bn)
      s += lg[bn * 8 + h] * (float)((const half_t*)((const char*)lv + bn * 528))[c];
    out[(size_t)na * 256 + c] = a[(size_t)na * 256 + c] + s;
  }
}

// ---------------------------------------------------------------- launch

extern "C" void kernel_launch(void* const* d_in, const int* in_sizes, int n_in,
                              void* d_out, int out_size, void* d_ws, size_t ws_size,
                              hipStream_t stream)
{
  const float* a    = (const float*)d_in[0];
  const float* b    = (const float*)d_in[1];
  const int*   mask = (const int*)d_in[2];
  const float* rbf  = (const float*)d_in[3];
  const float* q_w1 = (const float*)d_in[4];
  const float* q_b1 = (const float*)d_in[5];
  const float* q_w2 = (const float*)d_in[6];
  const float* q_b2 = (const float*)d_in[7];
  const float* k_w1 = (const float*)d_in[8];
  const float* k_b1 = (const float*)d_in[9];
  const float* k_w2 = (const float*)d_in[10];
  const float* k_b2 = (const float*)d_in[11];
  const float* v_w1 = (const float*)d_in[12];
  const float* v_b1 = (const float*)d_in[13];
  const float* v_w2 = (const float*)d_in[14];
  const float* v_b2 = (const float*)d_in[15];
  float* out = (float*)d_out;

  half_t* Xv   = (half_t*)d_ws;                          // [147456][512]
  half_t* kb   = Xv   + (size_t)R_ROWS * 512;            // [147456][256]
  half_t* vb   = kb   + (size_t)R_ROWS * 256;            // [147456][256]
  half_t* ah   = vb   + (size_t)R_ROWS * 256;            // [3072][256]
  half_t* qh   = ah   + (size_t)Q_ROWS * 256;            // [3072][256]
  half_t* qw1t = qh   + (size_t)Q_ROWS * 256;            // [512][256]
  half_t* qw2t = qw1t + 256 * 512;                       // [256][512]
  half_t* kw1t = qw2t + 512 * 256;                       // [512][256]
  half_t* kw2t = kw1t + 256 * 512;                       // [256][512]
  half_t* vw1t = kw2t + 512 * 256;                       // [512][512]
  half_t* vw2t = vw1t + 512 * 512;                       // [256][512]
  (void)in_sizes; (void)n_in; (void)out_size; (void)ws_size;

  // prep
  build_xv<<<R_ROWS * 32 / 256, 256, 0, stream>>>(b, rbf, Xv);
  cvt_f32_f16<<<(Q_ROWS * 32 + 255) / 256, 256, 0, stream>>>(a, ah, Q_ROWS * 32);
  prep_wt<<<512,  256, 0, stream>>>(q_w1, qw1t, 256, 512);
  prep_wt<<<512,  256, 0, stream>>>(q_w2, qw2t, 512, 256);
  prep_wt<<<512,  256, 0, stream>>>(k_w1, kw1t, 256, 512);
  prep_wt<<<512,  256, 0, stream>>>(k_w2, kw2t, 512, 256);
  prep_wt<<<1024, 256, 0, stream>>>(v_w1, vw1t, 512, 512);
  prep_wt<<<512,  256, 0, stream>>>(v_w2, vw2t, 512, 256);

  // fused MLPs: q (M=3072), k (M=147456, K1=256), v (M=147456, K1=512)
  fused_mlp<4><<<Q_ROWS / 128, 256, 0, stream>>>(ah, 256, qw1t, q_b1, qw2t, q_b2, qh);
  fused_mlp<4><<<R_ROWS / 128, 256, 0, stream>>>(Xv, 512, kw1t, k_b1, kw2t, k_b2, kb);
  fused_mlp<8><<<R_ROWS / 128, 256, 0, stream>>>(Xv, 512, vw1t, v_b1, vw2t, v_b2, vb);
  // fused attention + residual
  attn_kernel<<<Q_ROWS, 128, 0, stream>>>(qh, kb, vb, mask, a, out);
}

// Round 4
// 920.229 us; speedup vs baseline: 1.6058x; 1.6058x over previous
//
#include <hip/hip_runtime.h>
#include <hip/hip_fp16.h>

// NonLinearAttention on MI355X (gfx950), round 4.
// Shapes: N=32 mol, A=96 atoms, B=48 neighbors, F=256, D=256, H=8 heads, d=32.
// R3 post-mortem: fused MLP = 203 TF eff (MfmaUtil 8%, Occ 18%, latency-bound).
// R4: UNFUSED m97-structure GEMMs (32KB LDS -> 3 blocks/CU, 2-barrier K-loop,
// global_load_lds w=16). Hidden H materialized in QUARTERS to cap ws at ~348MB.
// Workspace:
//   Xv [147456][512] fp16 = fp16(b)||fp16(rbf)  151.0 MB
//   kb [147456][256] fp16                         75.5 MB
//   vb [147456][256] fp16                         75.5 MB
//   Hq [36864][512] fp16 (quarter hidden, reused) 37.75 MB
//   q-path bufs + 6 transposed weights            ~5 MB      => ~348 MB

using half_t = _Float16;
using half8  = __attribute__((ext_vector_type(8))) _Float16;
using f32x4  = __attribute__((ext_vector_type(4))) float;

#define R_ROWS 147456   // N*A*B
#define Q_ROWS 3072     // N*A
#define QTR    36864    // R_ROWS/4

// async global->LDS, 16B/lane; LDS dest wave-uniform (HW adds lane*16).
__device__ __forceinline__ void gld_lds16(const void* g, void* l) {
  __builtin_amdgcn_global_load_lds((const __attribute__((address_space(1))) void*)g,
                                   (__attribute__((address_space(3))) void*)l,
                                   16, 0, 0);
}

// ---------------------------------------------------------------- prep kernels

__global__ __launch_bounds__(256)
void build_xv(const float* __restrict__ b, const float* __restrict__ rbf,
              half_t* __restrict__ xv)
{
  int i  = blockIdx.x * 256 + threadIdx.x;
  int r  = i >> 5;
  int c8 = (i & 31) << 3;
  const float4* pb = (const float4*)(b   + (size_t)r * 256 + c8);
  const float4* pr = (const float4*)(rbf + (size_t)r * 256 + c8);
  float4 b0 = pb[0], b1 = pb[1];
  float4 r0 = pr[0], r1 = pr[1];
  union { half_t h[8]; uint4 u; } k0, k1;
  k0.h[0]=(half_t)b0.x; k0.h[1]=(half_t)b0.y; k0.h[2]=(half_t)b0.z; k0.h[3]=(half_t)b0.w;
  k0.h[4]=(half_t)b1.x; k0.h[5]=(half_t)b1.y; k0.h[6]=(half_t)b1.z; k0.h[7]=(half_t)b1.w;
  k1.h[0]=(half_t)r0.x; k1.h[1]=(half_t)r0.y; k1.h[2]=(half_t)r0.z; k1.h[3]=(half_t)r0.w;
  k1.h[4]=(half_t)r1.x; k1.h[5]=(half_t)r1.y; k1.h[6]=(half_t)r1.z; k1.h[7]=(half_t)r1.w;
  *(uint4*)(xv + (size_t)r * 512 + c8)       = k0.u;
  *(uint4*)(xv + (size_t)r * 512 + 256 + c8) = k1.u;
}

__global__ __launch_bounds__(256)
void cvt_f32_f16(const float* __restrict__ in, half_t* __restrict__ o, int n8)
{
  int i = blockIdx.x * 256 + threadIdx.x;
  if (i >= n8) return;
  const float4* p = (const float4*)(in + (size_t)i * 8);
  float4 a0 = p[0], a1 = p[1];
  union { half_t h[8]; uint4 u; } k;
  k.h[0]=(half_t)a0.x; k.h[1]=(half_t)a0.y; k.h[2]=(half_t)a0.z; k.h[3]=(half_t)a0.w;
  k.h[4]=(half_t)a1.x; k.h[5]=(half_t)a1.y; k.h[6]=(half_t)a1.z; k.h[7]=(half_t)a1.w;
  *(uint4*)(o + (size_t)i * 8) = k.u;
}

// W[K][N] fp32 -> WT[N][K] fp16.
__global__ __launch_bounds__(256)
void prep_wt(const float* __restrict__ w, half_t* __restrict__ wt, int K, int N)
{
  int i = blockIdx.x * 256 + threadIdx.x;
  if (i >= K * N) return;
  int n = i / K, k = i % K;
  wt[i] = (half_t)w[(size_t)k * N + n];
}

// ---------------------------------------------------------------- GEMM engine
// O[M][ldo(:128-block)] = act(X[M][:K] @ W + bias), W pre-transposed WT[N][K].
// m97 structure verbatim: 128x128 tile, 4 waves (2x2), BK=64, linear LDS
// [row][64 halfs], global_load_lds dwordx4 staging (wave-uniform LDS base),
// 2 barriers per K-step, mfma_f32_16x16x32_f16, 32KB LDS -> 3 blocks/CU.
// A/B k-permutation is consistent (both k = s*32 + (lane>>4)*8).
template<int KTILES, bool RELU>
__global__ __launch_bounds__(256)
void mlp_gemm(const half_t* __restrict__ X, int ldx,
              const half_t* __restrict__ WT,
              const float* __restrict__ bias,
              half_t* __restrict__ O, int ldo)
{
  __shared__ __align__(16) half_t lx[128 * 64];
  __shared__ __align__(16) half_t lw[128 * 64];
  const int tid  = threadIdx.x;
  const int lane = tid & 63;
  const int wid  = tid >> 6;
  const int wr   = (wid >> 1) * 64;
  const int wc   = (wid & 1) * 64;
  const int mt   = blockIdx.y * 128;
  const int nt   = blockIdx.x * 128;
  const int l15  = lane & 15;
  const int lg   = lane >> 4;
  const int srow = lane >> 3;          // staging: row within 8-row chunk
  const int sbyt = (lane & 7) * 16;    // staging: byte within 128B row

  f32x4 acc[4][4];
#pragma unroll
  for (int i = 0; i < 4; ++i)
#pragma unroll
    for (int j = 0; j < 4; ++j)
      acc[i][j] = (f32x4){0.f, 0.f, 0.f, 0.f};

  for (int kt = 0; kt < KTILES; ++kt) {
    const int k0 = kt * 64;
#pragma unroll
    for (int it = 0; it < 4; ++it) {
      const int rbase = wid * 32 + it * 8;             // wave-uniform LDS row base
      const int grow  = rbase + srow;                  // per-lane global row
      gld_lds16((const char*)(X + (size_t)(mt + grow) * ldx + k0) + sbyt,
                (char*)lx + rbase * 128);
      gld_lds16((const char*)(WT + (size_t)(nt + grow) * (KTILES * 64) + k0) + sbyt,
                (char*)lw + rbase * 128);
    }
    __syncthreads();
#pragma unroll
    for (int s = 0; s < 2; ++s) {
      const int kk2 = s * 32 + lg * 8;
      half8 af[4], bf[4];
#pragma unroll
      for (int i = 0; i < 4; ++i)
        af[i] = *(const half8*)(lx + (wr + i * 16 + l15) * 64 + kk2);
#pragma unroll
      for (int j = 0; j < 4; ++j)
        bf[j] = *(const half8*)(lw + (wc + j * 16 + l15) * 64 + kk2);
#pragma unroll
      for (int i = 0; i < 4; ++i)
#pragma unroll
        for (int j = 0; j < 4; ++j)
          acc[i][j] = __builtin_amdgcn_mfma_f32_16x16x32_f16(af[i], bf[j], acc[i][j], 0, 0, 0);
    }
    __syncthreads();
  }

  // Epilogue. C/D layout (verified m89/m91): col = lane&15, row = (lane>>4)*4+reg.
#pragma unroll
  for (int j = 0; j < 4; ++j) {
    const int gc = nt + wc + j * 16 + l15;
    const float bv = bias[gc];
#pragma unroll
    for (int i = 0; i < 4; ++i) {
      const int gr0 = mt + wr + i * 16 + lg * 4;
#pragma unroll
      for (int r = 0; r < 4; ++r) {
        float vvv = acc[i][j][r] + bv;
        if (RELU) vvv = fmaxf(vvv, 0.f);
        O[(size_t)(gr0 + r) * ldo + gc] = (half_t)vvv;
      }
    }
  }
}

// ---------------------------------------------------------------- attention
// One block (128 thr) per (n,a). Stage k,v (48x256 fp16) in padded LDS,
// logits+mask, per-head softmax over 48 neighbors, PV, residual. fp32 math.
__global__ __launch_bounds__(128)
void attn_kernel(const half_t* __restrict__ q,
                 const half_t* __restrict__ kk,
                 const half_t* __restrict__ vv,
                 const int* __restrict__ mask,
                 const float* __restrict__ a,
                 float* __restrict__ out)
{
  __shared__ __align__(16) half_t lk[48 * 264];
  __shared__ __align__(16) half_t lv[48 * 264];
  __shared__ float lq[8 * 36];
  __shared__ float lg[48 * 8];
  const int na = blockIdx.x;
  const int t  = threadIdx.x;
  const size_t base = (size_t)na * (48 * 256);

#pragma unroll
  for (int it = 0; it < 12; ++it) {
    int c = it * 128 + t;
    int row = c >> 5, c16 = (c & 31) * 16;
    uint4 dk = ((const uint4*)(kk + base))[c];
    uint4 dv = ((const uint4*)(vv + base))[c];
    *(uint4*)((char*)lk + row * 528 + c16) = dk;
    *(uint4*)((char*)lv + row * 528 + c16) = dv;
  }
  {
    float q0 = (float)q[(size_t)na * 256 + t];
    float q1 = (float)q[(size_t)na * 256 + 128 + t];
    int h0 = t >> 5, d0 = t & 31;
    lq[h0 * 36 + d0]       = q0;
    lq[(h0 + 4) * 36 + d0] = q1;
  }
  __syncthreads();

#pragma unroll
  for (int p = 0; p < 3; ++p) {
    int pr = p * 128 + t;
    int bn = pr >> 3, h = pr & 7;
    const half_t* kr = (const half_t*)((const char*)lk + bn * 528) + h * 32;
    const float*  qr = lq + h * 36;
    float s = 0.f;
#pragma unroll
    for (int d = 0; d < 32; ++d) s += qr[d] * (float)kr[d];
    if (mask[na * 48 + bn] == 0) s -= 100000.0f;
    lg[bn * 8 + h] = s;
  }
  __syncthreads();
  if (t < 8) {
    float mx = -3.0e38f;
    for (int bn = 0; bn < 48; ++bn) mx = fmaxf(mx, lg[bn * 8 + t]);
    float sm = 0.f;
    for (int bn = 0; bn < 48; ++bn) {
      float e = __expf(lg[bn * 8 + t] - mx);
      lg[bn * 8 + t] = e; sm += e;
    }
    float inv = 1.f / sm;
    for (int bn = 0; bn < 48; ++bn) lg[bn * 8 + t] *= inv;
  }
  __syncthreads();
#pragma unroll
  for (int cc = 0; cc < 2; ++cc) {
    int c = cc * 128 + t;
    int h = c >> 5;
    float s = 0.f;
#pragma unroll
    for (int bn = 0; bn < 48; ++bn)
      s += lg[bn * 8 + h] * (float)((const half_t*)((const char*)lv + bn * 528))[c];
    out[(size_t)na * 256 + c] = a[(size_t)na * 256 + c] + s;
  }
}

// ---------------------------------------------------------------- launch

extern "C" void kernel_launch(void* const* d_in, const int* in_sizes, int n_in,
                              void* d_out, int out_size, void* d_ws, size_t ws_size,
                              hipStream_t stream)
{
  const float* a    = (const float*)d_in[0];
  const float* b    = (const float*)d_in[1];
  const int*   mask = (const int*)d_in[2];
  const float* rbf  = (const float*)d_in[3];
  const float* q_w1 = (const float*)d_in[4];
  const float* q_b1 = (const float*)d_in[5];
  const float* q_w2 = (const float*)d_in[6];
  const float* q_b2 = (const float*)d_in[7];
  const float* k_w1 = (const float*)d_in[8];
  const float* k_b1 = (const float*)d_in[9];
  const float* k_w2 = (const float*)d_in[10];
  const float* k_b2 = (const float*)d_in[11];
  const float* v_w1 = (const float*)d_in[12];
  const float* v_b1 = (const float*)d_in[13];
  const float* v_w2 = (const float*)d_in[14];
  const float* v_b2 = (const float*)d_in[15];
  float* out = (float*)d_out;

  half_t* Xv   = (half_t*)d_ws;                          // [147456][512]
  half_t* kb   = Xv   + (size_t)R_ROWS * 512;            // [147456][256]
  half_t* vb   = kb   + (size_t)R_ROWS * 256;            // [147456][256]
  half_t* Hq   = vb   + (size_t)R_ROWS * 256;            // [36864][512] reused 8x
  half_t* ah   = Hq   + (size_t)QTR * 512;               // [3072][256]
  half_t* qh   = ah   + (size_t)Q_ROWS * 256;            // [3072][256]
  half_t* Hq3k = qh   + (size_t)Q_ROWS * 256;            // [3072][512]
  half_t* qw1t = Hq3k + (size_t)Q_ROWS * 512;            // [512][256]
  half_t* qw2t = qw1t + 256 * 512;                       // [256][512]
  half_t* kw1t = qw2t + 512 * 256;                       // [512][256]
  half_t* kw2t = kw1t + 256 * 512;                       // [256][512]
  half_t* vw1t = kw2t + 512 * 256;                       // [512][512]
  half_t* vw2t = vw1t + 512 * 512;                       // [256][512]
  (void)in_sizes; (void)n_in; (void)out_size; (void)ws_size;

  // prep
  build_xv<<<R_ROWS * 32 / 256, 256, 0, stream>>>(b, rbf, Xv);
  cvt_f32_f16<<<(Q_ROWS * 32 + 255) / 256, 256, 0, stream>>>(a, ah, Q_ROWS * 32);
  prep_wt<<<512,  256, 0, stream>>>(q_w1, qw1t, 256, 512);
  prep_wt<<<512,  256, 0, stream>>>(q_w2, qw2t, 512, 256);
  prep_wt<<<512,  256, 0, stream>>>(k_w1, kw1t, 256, 512);
  prep_wt<<<512,  256, 0, stream>>>(k_w2, kw2t, 512, 256);
  prep_wt<<<1024, 256, 0, stream>>>(v_w1, vw1t, 512, 512);
  prep_wt<<<512,  256, 0, stream>>>(v_w2, vw2t, 512, 256);

  dim3 blk(256);
  // q path (M=3072): K1=256 (reads ah), K2=512
  mlp_gemm<4, true ><<<dim3(4, Q_ROWS / 128), blk, 0, stream>>>(ah, 256, qw1t, q_b1, Hq3k, 512);
  mlp_gemm<8, false><<<dim3(2, Q_ROWS / 128), blk, 0, stream>>>(Hq3k, 512, qw2t, q_b2, qh, 256);

  // k and v paths in quarters of M (H buffer reused; stream-ordered)
  for (int q4 = 0; q4 < 4; ++q4) {
    const half_t* Xq = Xv + (size_t)q4 * QTR * 512;
    half_t* kbq = kb + (size_t)q4 * QTR * 256;
    half_t* vbq = vb + (size_t)q4 * QTR * 256;
    // k: L1 reads Xv cols 0-255 (ldx=512, KTILES=4), L2 K=512
    mlp_gemm<4, true ><<<dim3(4, QTR / 128), blk, 0, stream>>>(Xq, 512, kw1t, k_b1, Hq, 512);
    mlp_gemm<8, false><<<dim3(2, QTR / 128), blk, 0, stream>>>(Hq, 512, kw2t, k_b2, kbq, 256);
    // v: L1 reads full Xv rows (K=512), L2 K=512
    mlp_gemm<8, true ><<<dim3(4, QTR / 128), blk, 0, stream>>>(Xq, 512, vw1t, v_b1, Hq, 512);
    mlp_gemm<8, false><<<dim3(2, QTR / 128), blk, 0, stream>>>(Hq, 512, vw2t, v_b2, vbq, 256);
  }

  // fused attention + residual
  attn_kernel<<<Q_ROWS, 128, 0, stream>>>(qh, kb, vb, mask, a, out);
}